// Round 2
// baseline (774.412 us; speedup 1.0000x reference)
//
#include <hip/hip_runtime.h>
#include <stdint.h>

#define TT 1024
#define AL 0.05f
#define OM 0.95f
#define STRD 408   // padded [c][.] row stride
#define LOG2E 1.4426950408889634f

typedef short s4v __attribute__((ext_vector_type(4)));
typedef short s8v __attribute__((ext_vector_type(8)));
typedef float f4v __attribute__((ext_vector_type(4)));
typedef float f16v __attribute__((ext_vector_type(16)));
typedef int   i2v __attribute__((ext_vector_type(2)));

#define MF32(a,b,c) __builtin_amdgcn_mfma_f32_32x32x16_bf16(a,b,c,0,0,0)
#define MF16(a,b,c) __builtin_amdgcn_mfma_f32_16x16x32_bf16(a,b,c,0,0,0)

#if __has_builtin(__builtin_amdgcn_exp2f)
#define E2(x) __builtin_amdgcn_exp2f(x)
#else
#define E2(x) exp2f(x)
#endif

__device__ __forceinline__ uint16_t f2bf(float f){ union{float f;uint32_t i;}t; t.f=f; return (uint16_t)((t.i + 0x7fffu + ((t.i>>16)&1u))>>16); }
__device__ __forceinline__ float bf2f(uint16_t h){ union{uint32_t i;float f;}t; t.i=((uint32_t)h)<<16; return t.f; }
__device__ __forceinline__ float bfLO(uint32_t u){ union{uint32_t i;float f;}t; t.i=u<<16; return t.f; }
__device__ __forceinline__ float bfHI(uint32_t u){ union{uint32_t i;float f;}t; t.i=u&0xffff0000u; return t.f; }
// packed f32->bf16 (RNE, same semantics as f2bf), 1 inst per pair
__device__ __forceinline__ uint32_t cvtpk(float lo, float hi){ uint32_t r; asm("v_cvt_pk_bf16_f32 %0, %1, %2" : "=v"(r) : "v"(lo), "v"(hi)); return r; }
// exchange hi-half(x) <-> lo-half(y) across the lane32 boundary
__device__ __forceinline__ void pl32swap(uint32_t &x, uint32_t &y){
#if __has_builtin(__builtin_amdgcn_permlane32_swap)
  i2v rr = __builtin_amdgcn_permlane32_swap((int)x, (int)y, false, false);
  x = (uint32_t)rr.x; y = (uint32_t)rr.y;
#else
  asm("v_permlane32_swap_b32 %0, %1" : "+v"(x), "+v"(y));
#endif
}
// tanh(x) = 1 - 2/(1+e^{2x}) : 5 VALU ops vs libm tanhf
__device__ __forceinline__ float ftanh(float x){ float t = E2(2.885390081777927f*x); return __builtin_fmaf(-2.f, __builtin_amdgcn_rcpf(1.f + t), 1.f); }
__device__ __forceinline__ s8v ld8(const uint16_t* p){ return *(const s8v*)p; }
__device__ __forceinline__ s8v ld8u(const uint16_t* p){
  s4v lo = *(const s4v*)p; s4v hi = *(const s4v*)(p+4);
  return __builtin_shufflevector(lo, hi, 0,1,2,3,4,5,6,7);
}
#define ROWF(e2) (((e2)&3) + 8*((e2)>>2) + 4*h2)
// bank-conflict swizzle for [v][32] u16 buffers: XOR u16-idx bits 3-5 with v&7.
#define VXA(row,off) ((((row)<<5) + (off)) ^ (((row)&7)<<3))

// staging buffer for output transpose
__device__ __align__(16) float gStage[32*12*12800];

// S map (u16), total 81568 = 163.1 KB
#define X1S 0
#define X2S 12800
#define XCV 25600
#define PBA 38656
#define HCV 54656
#define GCV 67712
#define RINV 80768
#define CINV 81168

__global__ __launch_bounds__(TT, 4) void dymix(
    const float* __restrict__ x,
    const float* __restrict__ w1, const float* __restrict__ b1,
    const float* __restrict__ w2, const float* __restrict__ b2,
    const float* __restrict__ wm1, const float* __restrict__ bm1,
    const float* __restrict__ wm2, const float* __restrict__ bm2)
{
  __shared__ __align__(16) uint16_t S[81568];

  const int blk = blockIdx.x;
  const int xcd = blk & 7, slot = blk >> 3;    // group 12 l-blocks of each n per XCD
  const int n = xcd*4 + slot/12;
  const int l = slot - (slot/12)*12;
  const int t = threadIdx.x;
  const int wv = t >> 6;        // 0..15
  const int lane = t & 63;
  const int q  = lane >> 4;
  const int r  = lane & 15;
  const int h2 = lane >> 5;
  const int m32 = lane & 31;
  const long xbase = (long)n*153600 + l;

  // ---------- Phase 0: stage X -> XCV [c][408] ----------
  for (int i = t; i < 12800; i += TT) {
    int c = i / 400, v = i - c*400;
    S[XCV + c*STRD + v] = f2bf(x[xbase + (long)i*12]);
  }
  __syncthreads();

  // ---------- Phase L prep: XT (swizzled [v][32]) + lin weights into PBA ----------
  for (int i = t; i < 12800; i += TT) { int v = i>>5, c = i&31; S[PBA + VXA(v,c)] = S[XCV + c*STRD + v]; }
  for (int i = t; i < 1024; i += TT) {
    int o = i>>5, c = i&31;
    S[PBA + 12800 + o*40 + c] = f2bf(w1[i]);
    S[PBA + 14080 + o*40 + c] = f2bf(w2[i]);
  }
  if (t < 32) { ((float*)(S+PBA+15360))[t] = b1[t]; ((float*)(S+PBA+15424))[t] = b2[t]; }
  __syncthreads();

  // ---------- Phase L: x1 = log2e*tanh(W1 X + b1), x2 = tanh(W2 X + b2) -> swizzled [v][32] ----------
  #pragma unroll
  for (int j = 0; j < 2; ++j) {
    int u = wv + 16*j;
    if (u < 24) {
      int nt = u >> 1, li = u & 1;
      const uint16_t* W = S + PBA + 12800 + li*1280;
      const float* bfp = (const float*)(S + PBA + 15360 + li*64);
      uint16_t* dst = S + (li ? X2S : X1S);
      const float osc = li ? 1.f : LOG2E;
      f16v z = {};
      #pragma unroll
      for (int kk = 0; kk < 2; ++kk) {
        s8v a = ld8(W + m32*40 + kk*16 + h2*8);
        s8v b = ld8(S + PBA + VXA(nt*32 + m32, kk*16 + h2*8));
        z = MF32(a, b, z);
      }
      int v = nt*32 + m32;
      #pragma unroll
      for (int g = 0; g < 4; ++g) {
        float p0 = ftanh(z[4*g+0] + bfp[8*g+4*h2+0]) * osc;
        float p1 = ftanh(z[4*g+1] + bfp[8*g+4*h2+1]) * osc;
        float p2 = ftanh(z[4*g+2] + bfp[8*g+4*h2+2]) * osc;
        float p3 = ftanh(z[4*g+3] + bfp[8*g+4*h2+3]) * osc;
        uint2 d; d.x = cvtpk(p0,p1); d.y = cvtpk(p2,p3);
        *(uint2*)(dst + VXA(v, 8*g + 4*h2)) = d;
      }
    } else if (u < 28) {
      int li = (u-24)>>1, mt = u&1;
      const uint16_t* W = S + PBA + 12800 + li*1280;
      const float* bfp = (const float*)(S + PBA + 15360 + li*64);
      uint16_t* dst = S + (li ? X2S : X1S);
      const float osc = li ? 1.f : LOG2E;
      s8v a = ld8(W + (mt*16 + r)*40 + q*8);
      s8v b = ld8(S + PBA + VXA(384 + r, q*8));
      f4v z4 = {}; z4 = MF16(a, b, z4);
      float p0 = ftanh(z4[0] + bfp[mt*16+q*4+0]) * osc;
      float p1 = ftanh(z4[1] + bfp[mt*16+q*4+1]) * osc;
      float p2 = ftanh(z4[2] + bfp[mt*16+q*4+2]) * osc;
      float p3 = ftanh(z4[3] + bfp[mt*16+q*4+3]) * osc;
      uint2 d; d.x = cvtpk(p0,p1); d.y = cvtpk(p2,p3);
      *(uint2*)(dst + VXA(384 + r, mt*16 + q*4)) = d;
    }
  }
  // preload MLP X b-frags from XT (XT dies when diffusion starts)
  s8v xf0, xf1, xft;
  {
    int m0 = (wv < 12) ? wv : 0;
    xf0 = ld8(S + PBA + VXA(m0*32 + m32, h2*8));
    xf1 = ld8(S + PBA + VXA(m0*32 + m32, 16 + h2*8));
    xft = ld8(S + PBA + VXA(384 + r, q*8));
  }
  __syncthreads();

  // ---------- Stats: rowsum/colsum of exp2(A') ----------
  float* rsf = (float*)(S + HCV);
  float* csf = rsf + 400;
  for (int i = t; i < 400; i += TT) csf[i] = 0.f;
  __syncthreads();
  {
    s8v av[2]; f4v rac[2] = {{},{}};
    #pragma unroll
    for (int jj = 0; jj < 2; ++jj) { int vt = wv + 16*jj; if (vt < 25) av[jj] = ld8(S + X1S + VXA(vt*16 + r, q*8)); }
    s8v bnx = ld8(S + X2S + VXA(r, q*8));   // wt=0 prefetch
    for (int wt = 0; wt < 25; ++wt) {
      s8v b = bnx;
      if (wt < 24) bnx = ld8(S + X2S + VXA((wt+1)*16 + r, q*8));
      float cp = 0.f;
      #pragma unroll
      for (int jj = 0; jj < 2; ++jj) {
        int vt = wv + 16*jj;
        if (vt < 25) {
          f4v z = {}; z = MF16(av[jj], b, z);
          #pragma unroll
          for (int e = 0; e < 4; ++e) { float ev = E2(z[e]); rac[jj][e] += ev; cp += ev; }
        }
      }
      cp += __shfl_xor(cp, 16); cp += __shfl_xor(cp, 32);
      if (q == 0) atomicAdd(&csf[wt*16 + r], cp);
    }
    #pragma unroll
    for (int jj = 0; jj < 2; ++jj) {
      int vt = wv + 16*jj;
      if (vt < 25) {
        #pragma unroll
        for (int e = 0; e < 4; ++e) {
          float s = rac[jj][e];
          s += __shfl_xor(s,1); s += __shfl_xor(s,2); s += __shfl_xor(s,4); s += __shfl_xor(s,8);
          if (r == 0) rsf[vt*16 + q*4 + e] = s;
        }
      }
    }
  }
  __syncthreads();
  for (int i = t; i < 400; i += TT) { S[RINV + i] = f2bf(1.f/rsf[i]); S[CINV + i] = f2bf(1.f/csf[i]); }
  __syncthreads();

  // ---------- Diffusion: wave-private producer/consumer units, zero intra-step barriers.
  // NEW this round: (1) loop-invariant b-frags hoisted to registers across BOTH steps
  // (compiler couldn't prove no-alias with tail P-stores, so it re-read them 26x);
  // (2) one-deep software pipeline across sb: next iteration's T a-frags, GEMM A-frags
  // and scale dwords issued during current exp/MFMA work; (3) setprio around GEMM MFMAs. ----------
  bool act_[2]; int ch_[2], uu_[2]; bool mn_[2];
  const uint16_t *saB[2], *sbB[2]; int sclB[2];
  #pragma unroll
  for (int jj = 0; jj < 2; ++jj) {
    int g = wv + 16*jj; act_[jj] = (g < 26);
    int ch = (g < 13) ? 0 : 1; ch_[jj] = ch; int u = g - 13*ch; uu_[jj] = u; mn_[jj] = (u < 12);
    saB[jj] = S + (ch ? X2S : X1S);   // m-operand: v-slab rows
    sbB[jj] = S + (ch ? X1S : X2S);   // n-operand: w-tile rows (sb-invariant!)
    sclB[jj] = ch ? CINV : RINV;
  }
  s8v hb0[2], hb1[2];
  #pragma unroll
  for (int jj = 0; jj < 2; ++jj) {
    if (!act_[jj]) continue;
    if (mn_[jj]) { hb0[jj] = ld8(sbB[jj] + VXA(uu_[jj]*32 + m32, h2*8)); hb1[jj] = ld8(sbB[jj] + VXA(uu_[jj]*32 + m32, 16 + h2*8)); }
    else          hb0[jj] = ld8(sbB[jj] + VXA(384 + r, q*8));
  }

  f16v acc[2];
  for (int step = 0; step < 2; ++step) {
    { f16v zv = {}; acc[0]=zv; acc[1]=zv; }
    const uint16_t* AH = S + (step ? HCV : XCV);
    const uint16_t* AG = S + (step ? GCV : XCV);
    uint16_t* P0 = S + (step ? 40256 : PBA);
    uint16_t* P1 = S + (step ? XCV : 53056);
    const uint16_t* Acv[2]; uint16_t* Pp[2];
    #pragma unroll
    for (int jj = 0; jj < 2; ++jj) { Acv[jj] = ch_[jj] ? AG : AH; Pp[jj] = ch_[jj] ? P1 : P0; }

    // prologue: loads for sb=0
    s8v ta0[2], ta1[2], gA0[2], gA1[2]; uint2 s01[2][2], s23[2][2];
    #pragma unroll
    for (int jj = 0; jj < 2; ++jj) {
      if (!(act_[jj] && mn_[jj])) continue;
      ta0[jj] = ld8(saB[jj] + VXA(m32, h2*8));
      ta1[jj] = ld8(saB[jj] + VXA(m32, 16 + h2*8));
      gA0[jj] = ld8(Acv[jj] + m32*STRD + h2*8);
      gA1[jj] = ld8(Acv[jj] + m32*STRD + 16 + h2*8);
      const uint16_t* sp = S + sclB[jj] + 4*h2;
      s01[jj][0] = *(const uint2*)(sp);      s23[jj][0] = *(const uint2*)(sp + 8);
      s01[jj][1] = *(const uint2*)(sp + 16); s23[jj][1] = *(const uint2*)(sp + 24);
    }
    #pragma unroll 2
    for (int sb = 0; sb < 13; ++sb) {
      const int vbase = sb*32;
      const bool lastsb = (sb == 12);
      const int kmax = lastsb ? 1 : 2;
      // ---- prefetch next sb (overlaps with T compute below) ----
      s8v nta0[2], nta1[2], ngA0[2], ngA1[2]; uint2 ns01[2][2], ns23[2][2];
      if (!lastsb) {
        const int nvb = vbase + 32;
        #pragma unroll
        for (int jj = 0; jj < 2; ++jj) {
          if (!(act_[jj] && mn_[jj])) continue;
          nta0[jj] = ld8(saB[jj] + VXA(nvb + m32, h2*8));
          nta1[jj] = ld8(saB[jj] + VXA(nvb + m32, 16 + h2*8));
          ngA0[jj] = ld8(Acv[jj] + m32*STRD + nvb + h2*8);
          ngA1[jj] = ld8(Acv[jj] + m32*STRD + nvb + 16 + h2*8);
          const uint16_t* sp = S + sclB[jj] + nvb + 4*h2;
          ns01[jj][0] = *(const uint2*)(sp);      ns23[jj][0] = *(const uint2*)(sp + 8);
          ns01[jj][1] = *(const uint2*)(sp + 16); ns23[jj][1] = *(const uint2*)(sp + 24);
        }
      }
      s8v fr[2][2];   // [jj][k] in-register P b-frags
      // ---- T: produce this wave's P (registers for main units, LDS for tail) ----
      #pragma unroll
      for (int jj = 0; jj < 2; ++jj) {
        if (!act_[jj]) continue;
        if (mn_[jj]) {
          f16v z = {}; z = MF32(ta0[jj], hb0[jj], z); z = MF32(ta1[jj], hb1[jj], z);
          #pragma unroll
          for (int k = 0; k < 2; ++k) {
            if (k < kmax) {
              uint32_t sAB = s01[jj][k].x, sCD = s01[jj][k].y, sEF = s23[jj][k].x, sGH = s23[jj][k].y;
              uint32_t C0 = cvtpk(E2(z[8*k+0])*bfLO(sAB), E2(z[8*k+1])*bfHI(sAB));
              uint32_t C1 = cvtpk(E2(z[8*k+2])*bfLO(sCD), E2(z[8*k+3])*bfHI(sCD));
              uint32_t C2 = cvtpk(E2(z[8*k+4])*bfLO(sEF), E2(z[8*k+5])*bfHI(sEF));
              uint32_t C3 = cvtpk(E2(z[8*k+6])*bfLO(sGH), E2(z[8*k+7])*bfHI(sGH));
              pl32swap(C0, C2);   // C0 -> dw0, C2 -> dw2
              pl32swap(C1, C3);   // C1 -> dw1, C3 -> dw3
              union { uint32_t d[4]; s8v v8; } F;
              F.d[0] = C0; F.d[1] = C1; F.d[2] = C2; F.d[3] = C3;
              fr[jj][k] = F.v8;
            }
          }
        } else {
          uint16_t* P = Pp[jj];
          const int scl = sclB[jj];
          int ctmax = lastsb ? 1 : 2;
          for (int ct = 0; ct < ctmax; ++ct) {
            s8v a = ld8(saB[jj] + VXA(vbase + ct*16 + r, q*8));
            f4v z4 = {}; z4 = MF16(a, hb0[jj], z4);
            float p0 = E2(z4[0]) * bf2f(S[scl + vbase + ct*16 + q*4 + 0]);
            float p1 = E2(z4[1]) * bf2f(S[scl + vbase + ct*16 + q*4 + 1]);
            float p2 = E2(z4[2]) * bf2f(S[scl + vbase + ct*16 + q*4 + 2]);
            float p3 = E2(z4[3]) * bf2f(S[scl + vbase + ct*16 + q*4 + 3]);
            uint2 d; d.x = cvtpk(p0,p1); d.y = cvtpk(p2,p3);
            *(uint2*)(P + (384 + r)*36 + ct*16 + q*4) = d;
          }
          if (lastsb && lane < 16) {
            uint2 z0 = {0u,0u};
            uint16_t* pz = P + (384 + lane)*36 + 16;
            *(uint2*)(pz) = z0; *(uint2*)(pz+4) = z0; *(uint2*)(pz+8) = z0; *(uint2*)(pz+12) = z0;
          }
        }
      }
      // ---- GEMM: consume this wave's own P (register frags / tail LDS) ----
      __builtin_amdgcn_s_setprio(1);
      #pragma unroll
      for (int jj = 0; jj < 2; ++jj) {
        if (!act_[jj]) continue;
        if (mn_[jj]) {
          acc[jj] = MF32(gA0[jj], fr[jj][0], acc[jj]);
          if (!lastsb) acc[jj] = MF32(gA1[jj], fr[jj][1], acc[jj]);
        } else {
          uint16_t* P = Pp[jj];
          const uint16_t* Ac = Acv[jj];
          #pragma unroll
          for (int mt2 = 0; mt2 < 2; ++mt2) {
            int koff = (lastsb && q >= 2) ? 0 : q*8;   // pad cols never written — NaN guard (×0 in P)
            s8v a = ld8(Ac + (mt2*16 + r)*STRD + vbase + koff);
            s8v b = ld8u(P + (384 + r)*36 + q*8);
            f4v c4 = { acc[jj][4*mt2+0], acc[jj][4*mt2+1], acc[jj][4*mt2+2], acc[jj][4*mt2+3] };
            c4 = MF16(a, b, c4);
            acc[jj][4*mt2+0]=c4[0]; acc[jj][4*mt2+1]=c4[1]; acc[jj][4*mt2+2]=c4[2]; acc[jj][4*mt2+3]=c4[3];
          }
        }
      }
      __builtin_amdgcn_s_setprio(0);
      // ---- rotate pipeline registers ----
      if (!lastsb) {
        #pragma unroll
        for (int jj = 0; jj < 2; ++jj) {
          ta0[jj]=nta0[jj]; ta1[jj]=nta1[jj]; gA0[jj]=ngA0[jj]; gA1[jj]=ngA1[jj];
          s01[jj][0]=ns01[jj][0]; s01[jj][1]=ns01[jj][1];
          s23[jj][0]=ns23[jj][0]; s23[jj][1]=ns23[jj][1];
        }
      }
    } // sb
    __syncthreads();
    if (step == 0) {
      // epilogue: H1/G1 = AL*X + OM*acc -> HCV/GCV [c][408]
      #pragma unroll
      for (int jj = 0; jj < 2; ++jj) {
        if (!act_[jj]) continue;
        uint16_t* dst = S + (ch_[jj] ? GCV : HCV);
        if (mn_[jj]) {
          int w = uu_[jj]*32 + m32;
          #pragma unroll
          for (int e2 = 0; e2 < 16; ++e2) {
            int c = ROWF(e2);
            dst[c*STRD + w] = f2bf(AL*bf2f(S[XCV + c*STRD + w]) + OM*acc[jj][e2]);
          }
        } else {
          int w = 384 + r;
          #pragma unroll
          for (int mt2 = 0; mt2 < 2; ++mt2)
            #pragma unroll
            for (int e = 0; e < 4; ++e) {
              int c = mt2*16 + q*4 + e;
              dst[c*STRD + w] = f2bf(AL*bf2f(S[XCV + c*STRD + w]) + OM*acc[jj][4*mt2+e]);
            }
        }
      }
      __syncthreads();
    }
  } // step

  // ---------- MLP prep: features to swizzled [v][32]; weights folded into HCV ----------
  for (int i = t; i < 12800; i += TT) {
    int v = i >> 5, c = i & 31;
    int d = VXA(v, c);
    S[X1S + d] = S[HCV + c*STRD + v];   // H1
    S[X2S + d] = S[GCV + c*STRD + v];   // G1
  }
  #pragma unroll
  for (int jj = 0; jj < 2; ++jj) {
    if (!act_[jj]) continue;
    uint16_t* dst = S + (ch_[jj] ? PBA : XCV);   // H2' -> XCV, G2' -> PBA  (as swizzled [v][32])
    if (mn_[jj]) {
      int w = uu_[jj]*32 + m32;
      #pragma unroll
      for (int gg = 0; gg < 4; ++gg) {
        uint2 d;
        d.x = cvtpk(OM*acc[jj][4*gg+0], OM*acc[jj][4*gg+1]);
        d.y = cvtpk(OM*acc[jj][4*gg+2], OM*acc[jj][4*gg+3]);
        *(uint2*)(dst + VXA(w, 8*gg + 4*h2)) = d;
      }
    } else {
      int w = 384 + r;
      #pragma unroll
      for (int mt2 = 0; mt2 < 2; ++mt2) {
        uint2 d;
        d.x = cvtpk(OM*acc[jj][4*mt2+0], OM*acc[jj][4*mt2+1]);
        d.y = cvtpk(OM*acc[jj][4*mt2+2], OM*acc[jj][4*mt2+3]);
        *(uint2*)(dst + VXA(w, mt2*16 + q*4)) = d;
      }
    }
  }
  __syncthreads();
  for (int i = t; i < 1024; i += TT) {
    int o = i >> 5, c = i & 31;
    float h2w = wm1[o*96 + 64 + c], g2w = wm2[o*96 + 64 + c];
    S[HCV +        o*40 + c] = f2bf(wm1[o*96 + c] + wm2[o*96 + c] + AL*(h2w + g2w));
    S[HCV + 1280 + o*40 + c] = f2bf(wm1[o*96 + 32 + c]);
    S[HCV + 2560 + o*40 + c] = f2bf(h2w);
    S[HCV + 3840 + o*40 + c] = f2bf(wm2[o*96 + 32 + c]);
    S[HCV + 5120 + o*40 + c] = f2bf(g2w);
  }
  if (t < 32) ((float*)(S + HCV + 6400))[t] = bm1[t] + bm2[t];
  __syncthreads();

  // ---------- MLP + coalesced staged store to gStage[n][l][o][v] ----------
  {
    const float* boF = (const float*)(S + HCV + 6400);
    float* oSl = gStage + (long)(n*12 + l)*12800;
    const int fb[5] = { 0, X1S, XCV, X2S, PBA };   // X(regs), H1, H2', G1, G2'
    int m = wv;
    if (m < 12) {
      f16v z = {};
      #pragma unroll
      for (int p = 0; p < 5; ++p) {
        #pragma unroll
        for (int kk = 0; kk < 2; ++kk) {
          s8v a = ld8(S + HCV + p*1280 + m32*40 + kk*16 + h2*8);
          s8v b;
          if (p == 0) b = kk ? xf1 : xf0;
          else        b = ld8(S + fb[p] + VXA(m*32 + m32, kk*16 + h2*8));
          z = MF32(a, b, z);
        }
      }
      int v = m*32 + m32;
      #pragma unroll
      for (int e2 = 0; e2 < 16; ++e2) {
        int o = ROWF(e2);
        oSl[o*400 + v] = z[e2] + boF[o];
      }
    } else if (m < 14) {
      int mt = m - 12;
      f4v z4 = {};
      #pragma unroll
      for (int p = 0; p < 5; ++p) {
        s8v a = ld8(S + HCV + p*1280 + (mt*16 + r)*40 + q*8);
        s8v b = (p == 0) ? xft : ld8(S + fb[p] + VXA(384 + r, q*8));
        z4 = MF16(a, b, z4);
      }
      #pragma unroll
      for (int e = 0; e < 4; ++e) {
        int o = mt*16 + q*4 + e;
        oSl[o*400 + 384 + r] = z4[e] + boF[o];
      }
    }
  }
}

// Plain transpose kernel: gStage[n][l][o][v] -> out[n][o][v][l] (both sides coalesced)
__global__ __launch_bounds__(256) void finT(float* __restrict__ out) {
  int idx = blockIdx.x*256 + threadIdx.x;      // n*12800 + ov
  int n = idx / 12800, ov = idx - n*12800;
  const float* src = gStage + (long)n*153600 + ov;
  float vals[12];
  #pragma unroll
  for (int l = 0; l < 12; ++l) vals[l] = src[(long)l*12800];
  float4* dst = (float4*)(out + (long)idx*12);
  dst[0] = make_float4(vals[0],vals[1],vals[2],vals[3]);
  dst[1] = make_float4(vals[4],vals[5],vals[6],vals[7]);
  dst[2] = make_float4(vals[8],vals[9],vals[10],vals[11]);
}

extern "C" void kernel_launch(void* const* d_in, const int* in_sizes, int n_in,
                              void* d_out, int out_size, void* d_ws, size_t ws_size,
                              hipStream_t stream) {
  (void)in_sizes; (void)n_in; (void)out_size; (void)d_ws; (void)ws_size;
  dymix<<<dim3(384), dim3(TT), 0, stream>>>(
      (const float*)d_in[0],
      (const float*)d_in[1], (const float*)d_in[2],
      (const float*)d_in[3], (const float*)d_in[4],
      (const float*)d_in[5], (const float*)d_in[6],
      (const float*)d_in[7], (const float*)d_in[8]);
  finT<<<dim3(1600), dim3(256), 0, stream>>>((float*)d_out);
}

// Round 4
// 242.522 us; speedup vs baseline: 3.1932x; 3.1932x over previous
//
#include <hip/hip_runtime.h>
#include <stdint.h>

#define TT 1024
#define AL 0.05f
#define OM 0.95f
#define STRD 408   // padded [c][.] row stride
#define LOG2E 1.4426950408889634f

typedef short s4v __attribute__((ext_vector_type(4)));
typedef short s8v __attribute__((ext_vector_type(8)));
typedef float f4v __attribute__((ext_vector_type(4)));
typedef float f16v __attribute__((ext_vector_type(16)));
typedef int   i2v __attribute__((ext_vector_type(2)));

#define MF32(a,b,c) __builtin_amdgcn_mfma_f32_32x32x16_bf16(a,b,c,0,0,0)
#define MF16(a,b,c) __builtin_amdgcn_mfma_f32_16x16x32_bf16(a,b,c,0,0,0)

#if __has_builtin(__builtin_amdgcn_exp2f)
#define E2(x) __builtin_amdgcn_exp2f(x)
#else
#define E2(x) exp2f(x)
#endif

__device__ __forceinline__ uint16_t f2bf(float f){ union{float f;uint32_t i;}t; t.f=f; return (uint16_t)((t.i + 0x7fffu + ((t.i>>16)&1u))>>16); }
__device__ __forceinline__ float bf2f(uint16_t h){ union{uint32_t i;float f;}t; t.i=((uint32_t)h)<<16; return t.f; }
__device__ __forceinline__ float bfLO(uint32_t u){ union{uint32_t i;float f;}t; t.i=u<<16; return t.f; }
__device__ __forceinline__ float bfHI(uint32_t u){ union{uint32_t i;float f;}t; t.i=u&0xffff0000u; return t.f; }
// packed f32->bf16 (RNE, same semantics as f2bf), 1 inst per pair
__device__ __forceinline__ uint32_t cvtpk(float lo, float hi){ uint32_t r; asm("v_cvt_pk_bf16_f32 %0, %1, %2" : "=v"(r) : "v"(lo), "v"(hi)); return r; }
// exchange hi-half(x) <-> lo-half(y) across the lane32 boundary
__device__ __forceinline__ void pl32swap(uint32_t &x, uint32_t &y){
#if __has_builtin(__builtin_amdgcn_permlane32_swap)
  i2v rr = __builtin_amdgcn_permlane32_swap((int)x, (int)y, false, false);
  x = (uint32_t)rr.x; y = (uint32_t)rr.y;
#else
  asm("v_permlane32_swap_b32 %0, %1" : "+v"(x), "+v"(y));
#endif
}
// tanh(x) = 1 - 2/(1+e^{2x}) : 5 VALU ops vs libm tanhf
__device__ __forceinline__ float ftanh(float x){ float t = E2(2.885390081777927f*x); return __builtin_fmaf(-2.f, __builtin_amdgcn_rcpf(1.f + t), 1.f); }
__device__ __forceinline__ s8v ld8(const uint16_t* p){ return *(const s8v*)p; }
__device__ __forceinline__ s8v ld8u(const uint16_t* p){
  s4v lo = *(const s4v*)p; s4v hi = *(const s4v*)(p+4);
  return __builtin_shufflevector(lo, hi, 0,1,2,3,4,5,6,7);
}
#define ROWF(e2) (((e2)&3) + 8*((e2)>>2) + 4*h2)
// bank-conflict swizzle for [v][32] u16 buffers: XOR u16-idx bits 3-5 with v&7.
#define VXA(row,off) ((((row)<<5) + (off)) ^ (((row)&7)<<3))

// staging buffer for output transpose
__device__ __align__(16) float gStage[32*12*12800];

// S map (u16), total 81568 = 163.1 KB
#define X1S 0
#define X2S 12800
#define XCV 25600
#define PBA 38656
#define HCV 54656
#define GCV 67712
#define RINV 80768
#define CINV 81168

__global__ __launch_bounds__(TT) void dymix(
    const float* __restrict__ x,
    const float* __restrict__ w1, const float* __restrict__ b1,
    const float* __restrict__ w2, const float* __restrict__ b2,
    const float* __restrict__ wm1, const float* __restrict__ bm1,
    const float* __restrict__ wm2, const float* __restrict__ bm2)
{
  __shared__ __align__(16) uint16_t S[81568];

  const int blk = blockIdx.x;
  const int xcd = blk & 7, slot = blk >> 3;    // group 12 l-blocks of each n per XCD
  const int n = xcd*4 + slot/12;
  const int l = slot - (slot/12)*12;
  const int t = threadIdx.x;
  const int wv = t >> 6;        // 0..15
  const int lane = t & 63;
  const int q  = lane >> 4;
  const int r  = lane & 15;
  const int h2 = lane >> 5;
  const int m32 = lane & 31;
  const long xbase = (long)n*153600 + l;

  // ---------- Phase 0: stage X -> XCV [c][408] ----------
  for (int i = t; i < 12800; i += TT) {
    int c = i / 400, v = i - c*400;
    S[XCV + c*STRD + v] = f2bf(x[xbase + (long)i*12]);
  }
  __syncthreads();

  // ---------- Phase L prep: XT (swizzled [v][32]) + lin weights into PBA ----------
  for (int i = t; i < 12800; i += TT) { int v = i>>5, c = i&31; S[PBA + VXA(v,c)] = S[XCV + c*STRD + v]; }
  for (int i = t; i < 1024; i += TT) {
    int o = i>>5, c = i&31;
    S[PBA + 12800 + o*40 + c] = f2bf(w1[i]);
    S[PBA + 14080 + o*40 + c] = f2bf(w2[i]);
  }
  if (t < 32) { ((float*)(S+PBA+15360))[t] = b1[t]; ((float*)(S+PBA+15424))[t] = b2[t]; }
  __syncthreads();

  // ---------- Phase L: x1 = log2e*tanh(W1 X + b1), x2 = tanh(W2 X + b2) -> swizzled [v][32] ----------
  #pragma unroll
  for (int j = 0; j < 2; ++j) {
    int u = wv + 16*j;
    if (u < 24) {
      int nt = u >> 1, li = u & 1;
      const uint16_t* W = S + PBA + 12800 + li*1280;
      const float* bfp = (const float*)(S + PBA + 15360 + li*64);
      uint16_t* dst = S + (li ? X2S : X1S);
      const float osc = li ? 1.f : LOG2E;
      f16v z = {};
      #pragma unroll
      for (int kk = 0; kk < 2; ++kk) {
        s8v a = ld8(W + m32*40 + kk*16 + h2*8);
        s8v b = ld8(S + PBA + VXA(nt*32 + m32, kk*16 + h2*8));
        z = MF32(a, b, z);
      }
      int v = nt*32 + m32;
      #pragma unroll
      for (int g = 0; g < 4; ++g) {
        float p0 = ftanh(z[4*g+0] + bfp[8*g+4*h2+0]) * osc;
        float p1 = ftanh(z[4*g+1] + bfp[8*g+4*h2+1]) * osc;
        float p2 = ftanh(z[4*g+2] + bfp[8*g+4*h2+2]) * osc;
        float p3 = ftanh(z[4*g+3] + bfp[8*g+4*h2+3]) * osc;
        uint2 d; d.x = cvtpk(p0,p1); d.y = cvtpk(p2,p3);
        *(uint2*)(dst + VXA(v, 8*g + 4*h2)) = d;
      }
    } else if (u < 28) {
      int li = (u-24)>>1, mt = u&1;
      const uint16_t* W = S + PBA + 12800 + li*1280;
      const float* bfp = (const float*)(S + PBA + 15360 + li*64);
      uint16_t* dst = S + (li ? X2S : X1S);
      const float osc = li ? 1.f : LOG2E;
      s8v a = ld8(W + (mt*16 + r)*40 + q*8);
      s8v b = ld8(S + PBA + VXA(384 + r, q*8));
      f4v z4 = {}; z4 = MF16(a, b, z4);
      float p0 = ftanh(z4[0] + bfp[mt*16+q*4+0]) * osc;
      float p1 = ftanh(z4[1] + bfp[mt*16+q*4+1]) * osc;
      float p2 = ftanh(z4[2] + bfp[mt*16+q*4+2]) * osc;
      float p3 = ftanh(z4[3] + bfp[mt*16+q*4+3]) * osc;
      uint2 d; d.x = cvtpk(p0,p1); d.y = cvtpk(p2,p3);
      *(uint2*)(dst + VXA(384 + r, mt*16 + q*4)) = d;
    }
  }
  // preload MLP X b-frags from XT (XT dies when diffusion starts)
  s8v xf0, xf1, xft;
  {
    int m0 = (wv < 12) ? wv : 0;
    xf0 = ld8(S + PBA + VXA(m0*32 + m32, h2*8));
    xf1 = ld8(S + PBA + VXA(m0*32 + m32, 16 + h2*8));
    xft = ld8(S + PBA + VXA(384 + r, q*8));
  }
  __syncthreads();

  // ---------- Stats: rowsum/colsum of exp2(A') ----------
  float* rsf = (float*)(S + HCV);
  float* csf = rsf + 400;
  for (int i = t; i < 400; i += TT) csf[i] = 0.f;
  __syncthreads();
  {
    s8v av[2]; f4v rac[2] = {{},{}};
    #pragma unroll
    for (int jj = 0; jj < 2; ++jj) { int vt = wv + 16*jj; if (vt < 25) av[jj] = ld8(S + X1S + VXA(vt*16 + r, q*8)); }
    s8v bnx = ld8(S + X2S + VXA(r, q*8));   // wt=0 prefetch
    for (int wt = 0; wt < 25; ++wt) {
      s8v b = bnx;
      if (wt < 24) bnx = ld8(S + X2S + VXA((wt+1)*16 + r, q*8));
      float cp = 0.f;
      #pragma unroll
      for (int jj = 0; jj < 2; ++jj) {
        int vt = wv + 16*jj;
        if (vt < 25) {
          f4v z = {}; z = MF16(av[jj], b, z);
          #pragma unroll
          for (int e = 0; e < 4; ++e) { float ev = E2(z[e]); rac[jj][e] += ev; cp += ev; }
        }
      }
      cp += __shfl_xor(cp, 16); cp += __shfl_xor(cp, 32);
      if (q == 0) atomicAdd(&csf[wt*16 + r], cp);
    }
    #pragma unroll
    for (int jj = 0; jj < 2; ++jj) {
      int vt = wv + 16*jj;
      if (vt < 25) {
        #pragma unroll
        for (int e = 0; e < 4; ++e) {
          float s = rac[jj][e];
          s += __shfl_xor(s,1); s += __shfl_xor(s,2); s += __shfl_xor(s,4); s += __shfl_xor(s,8);
          if (r == 0) rsf[vt*16 + q*4 + e] = s;
        }
      }
    }
  }
  __syncthreads();
  for (int i = t; i < 400; i += TT) { S[RINV + i] = f2bf(1.f/rsf[i]); S[CINV + i] = f2bf(1.f/csf[i]); }
  __syncthreads();

  // ---------- Diffusion: wave-private producer/consumer units, zero intra-step barriers.
  // Round-3 deltas vs round-1 (round-2 pipeline reverted — it spilled to scratch, 2GB HBM):
  // (a) sb-invariant T b-frags hoisted to registers ONCE (compiler re-read them 26x/step
  //     because it can't prove no-alias with tail P-stores); (b) setprio around GEMM MFMAs.
  bool act_[2]; int ch_[2], uu_[2]; bool mn_[2];
  const uint16_t *saB[2], *sbB[2]; int sclB[2];
  #pragma unroll
  for (int jj = 0; jj < 2; ++jj) {
    int g = wv + 16*jj; act_[jj] = (g < 26);
    int ch = (g < 13) ? 0 : 1; ch_[jj] = ch; int u = g - 13*ch; uu_[jj] = u; mn_[jj] = (u < 12);
    saB[jj] = S + (ch ? X2S : X1S);   // m-operand: v-slab rows
    sbB[jj] = S + (ch ? X1S : X2S);   // n-operand: w-tile rows (sb-invariant!)
    sclB[jj] = ch ? CINV : RINV;
  }
  s8v hb0[2], hb1[2];
  #pragma unroll
  for (int jj = 0; jj < 2; ++jj) {
    if (!act_[jj]) continue;
    if (mn_[jj]) { hb0[jj] = ld8(sbB[jj] + VXA(uu_[jj]*32 + m32, h2*8)); hb1[jj] = ld8(sbB[jj] + VXA(uu_[jj]*32 + m32, 16 + h2*8)); }
    else          hb0[jj] = ld8(sbB[jj] + VXA(384 + r, q*8));
  }

  f16v acc[2];
  for (int step = 0; step < 2; ++step) {
    { f16v zv = {}; acc[0]=zv; acc[1]=zv; }
    const uint16_t* AH = S + (step ? HCV : XCV);
    const uint16_t* AG = S + (step ? GCV : XCV);
    uint16_t* P0 = S + (step ? 40256 : PBA);
    uint16_t* P1 = S + (step ? XCV : 53056);
    const uint16_t* Acv[2]; uint16_t* Pp[2];
    #pragma unroll
    for (int jj = 0; jj < 2; ++jj) { Acv[jj] = ch_[jj] ? AG : AH; Pp[jj] = ch_[jj] ? P1 : P0; }
    for (int sb = 0; sb < 13; ++sb) {
      const int vbase = sb*32;
      const bool lastsb = (sb == 12);
      const int kmax = lastsb ? 1 : 2;
      s8v fr[2][2];   // [jj][k] in-register P b-frags
      // ---- T: produce this wave's P (registers for main units, LDS for tail) ----
      #pragma unroll
      for (int jj = 0; jj < 2; ++jj) {
        if (!act_[jj]) continue;
        const int scl = sclB[jj];
        if (mn_[jj]) {
          s8v a0 = ld8(saB[jj] + VXA(vbase + m32, h2*8));
          s8v a1 = ld8(saB[jj] + VXA(vbase + m32, 16 + h2*8));
          f16v z = {}; z = MF32(a0, hb0[jj], z); z = MF32(a1, hb1[jj], z);
          #pragma unroll
          for (int k = 0; k < 2; ++k) {
            if (k < kmax) {
              const uint16_t* spt = S + scl + vbase + 16*k + 4*h2;
              uint32_t sAB = *(const uint32_t*)(spt);
              uint32_t sCD = *(const uint32_t*)(spt + 2);
              uint32_t sEF = *(const uint32_t*)(spt + 8);
              uint32_t sGH = *(const uint32_t*)(spt + 10);
              uint32_t C0 = cvtpk(E2(z[8*k+0])*bfLO(sAB), E2(z[8*k+1])*bfHI(sAB));
              uint32_t C1 = cvtpk(E2(z[8*k+2])*bfLO(sCD), E2(z[8*k+3])*bfHI(sCD));
              uint32_t C2 = cvtpk(E2(z[8*k+4])*bfLO(sEF), E2(z[8*k+5])*bfHI(sEF));
              uint32_t C3 = cvtpk(E2(z[8*k+6])*bfLO(sGH), E2(z[8*k+7])*bfHI(sGH));
              pl32swap(C0, C2);   // C0 -> dw0, C2 -> dw2
              pl32swap(C1, C3);   // C1 -> dw1, C3 -> dw3
              union { uint32_t d[4]; s8v v8; } F;
              F.d[0] = C0; F.d[1] = C1; F.d[2] = C2; F.d[3] = C3;
              fr[jj][k] = F.v8;
            }
          }
        } else {
          uint16_t* P = Pp[jj];
          int ctmax = lastsb ? 1 : 2;
          for (int ct = 0; ct < ctmax; ++ct) {
            s8v a = ld8(saB[jj] + VXA(vbase + ct*16 + r, q*8));
            f4v z4 = {}; z4 = MF16(a, hb0[jj], z4);
            float p0 = E2(z4[0]) * bf2f(S[scl + vbase + ct*16 + q*4 + 0]);
            float p1 = E2(z4[1]) * bf2f(S[scl + vbase + ct*16 + q*4 + 1]);
            float p2 = E2(z4[2]) * bf2f(S[scl + vbase + ct*16 + q*4 + 2]);
            float p3 = E2(z4[3]) * bf2f(S[scl + vbase + ct*16 + q*4 + 3]);
            uint2 d; d.x = cvtpk(p0,p1); d.y = cvtpk(p2,p3);
            *(uint2*)(P + (384 + r)*36 + ct*16 + q*4) = d;
          }
          if (lastsb && lane < 16) {
            uint2 z0 = {0u,0u};
            uint16_t* pz = P + (384 + lane)*36 + 16;
            *(uint2*)(pz) = z0; *(uint2*)(pz+4) = z0; *(uint2*)(pz+8) = z0; *(uint2*)(pz+12) = z0;
          }
        }
      }
      // ---- GEMM: consume this wave's own P (register frags / tail LDS) ----
      __builtin_amdgcn_s_setprio(1);
      #pragma unroll
      for (int jj = 0; jj < 2; ++jj) {
        if (!act_[jj]) continue;
        if (mn_[jj]) {
          #pragma unroll
          for (int k = 0; k < 2; ++k) {
            if (k < kmax) {
              s8v a = ld8(Acv[jj] + m32*STRD + vbase + k*16 + h2*8);
              acc[jj] = MF32(a, fr[jj][k], acc[jj]);
            }
          }
        } else {
          uint16_t* P = Pp[jj];
          #pragma unroll
          for (int mt2 = 0; mt2 < 2; ++mt2) {
            int koff = (lastsb && q >= 2) ? 0 : q*8;   // pad cols never written — NaN guard (×0 in P)
            s8v a = ld8(Acv[jj] + (mt2*16 + r)*STRD + vbase + koff);
            s8v b = ld8u(P + (384 + r)*36 + q*8);
            f4v c4 = { acc[jj][4*mt2+0], acc[jj][4*mt2+1], acc[jj][4*mt2+2], acc[jj][4*mt2+3] };
            c4 = MF16(a, b, c4);
            acc[jj][4*mt2+0]=c4[0]; acc[jj][4*mt2+1]=c4[1]; acc[jj][4*mt2+2]=c4[2]; acc[jj][4*mt2+3]=c4[3];
          }
        }
      }
      __builtin_amdgcn_s_setprio(0);
    } // sb
    __syncthreads();
    if (step == 0) {
      // epilogue: H1/G1 = AL*X + OM*acc -> HCV/GCV [c][408]
      #pragma unroll
      for (int jj = 0; jj < 2; ++jj) {
        if (!act_[jj]) continue;
        uint16_t* dst = S + (ch_[jj] ? GCV : HCV);
        if (mn_[jj]) {
          int w = uu_[jj]*32 + m32;
          #pragma unroll
          for (int e2 = 0; e2 < 16; ++e2) {
            int c = ROWF(e2);
            dst[c*STRD + w] = f2bf(AL*bf2f(S[XCV + c*STRD + w]) + OM*acc[jj][e2]);
          }
        } else {
          int w = 384 + r;
          #pragma unroll
          for (int mt2 = 0; mt2 < 2; ++mt2)
            #pragma unroll
            for (int e = 0; e < 4; ++e) {
              int c = mt2*16 + q*4 + e;
              dst[c*STRD + w] = f2bf(AL*bf2f(S[XCV + c*STRD + w]) + OM*acc[jj][4*mt2+e]);
            }
        }
      }
      __syncthreads();
    }
  } // step

  // ---------- MLP prep: features to swizzled [v][32]; weights folded into HCV ----------
  for (int i = t; i < 12800; i += TT) {
    int v = i >> 5, c = i & 31;
    int d = VXA(v, c);
    S[X1S + d] = S[HCV + c*STRD + v];   // H1
    S[X2S + d] = S[GCV + c*STRD + v];   // G1
  }
  #pragma unroll
  for (int jj = 0; jj < 2; ++jj) {
    if (!act_[jj]) continue;
    uint16_t* dst = S + (ch_[jj] ? PBA : XCV);   // H2' -> XCV, G2' -> PBA  (as swizzled [v][32])
    if (mn_[jj]) {
      int w = uu_[jj]*32 + m32;
      #pragma unroll
      for (int gg = 0; gg < 4; ++gg) {
        uint2 d;
        d.x = cvtpk(OM*acc[jj][4*gg+0], OM*acc[jj][4*gg+1]);
        d.y = cvtpk(OM*acc[jj][4*gg+2], OM*acc[jj][4*gg+3]);
        *(uint2*)(dst + VXA(w, 8*gg + 4*h2)) = d;
      }
    } else {
      int w = 384 + r;
      #pragma unroll
      for (int mt2 = 0; mt2 < 2; ++mt2) {
        uint2 d;
        d.x = cvtpk(OM*acc[jj][4*mt2+0], OM*acc[jj][4*mt2+1]);
        d.y = cvtpk(OM*acc[jj][4*mt2+2], OM*acc[jj][4*mt2+3]);
        *(uint2*)(dst + VXA(w, mt2*16 + q*4)) = d;
      }
    }
  }
  __syncthreads();
  for (int i = t; i < 1024; i += TT) {
    int o = i >> 5, c = i & 31;
    float h2w = wm1[o*96 + 64 + c], g2w = wm2[o*96 + 64 + c];
    S[HCV +        o*40 + c] = f2bf(wm1[o*96 + c] + wm2[o*96 + c] + AL*(h2w + g2w));
    S[HCV + 1280 + o*40 + c] = f2bf(wm1[o*96 + 32 + c]);
    S[HCV + 2560 + o*40 + c] = f2bf(h2w);
    S[HCV + 3840 + o*40 + c] = f2bf(wm2[o*96 + 32 + c]);
    S[HCV + 5120 + o*40 + c] = f2bf(g2w);
  }
  if (t < 32) ((float*)(S + HCV + 6400))[t] = bm1[t] + bm2[t];
  __syncthreads();

  // ---------- MLP + coalesced staged store to gStage[n][l][o][v] ----------
  {
    const float* boF = (const float*)(S + HCV + 6400);
    float* oSl = gStage + (long)(n*12 + l)*12800;
    const int fb[5] = { 0, X1S, XCV, X2S, PBA };   // X(regs), H1, H2', G1, G2'
    int m = wv;
    if (m < 12) {
      f16v z = {};
      #pragma unroll
      for (int p = 0; p < 5; ++p) {
        #pragma unroll
        for (int kk = 0; kk < 2; ++kk) {
          s8v a = ld8(S + HCV + p*1280 + m32*40 + kk*16 + h2*8);
          s8v b;
          if (p == 0) b = kk ? xf1 : xf0;
          else        b = ld8(S + fb[p] + VXA(m*32 + m32, kk*16 + h2*8));
          z = MF32(a, b, z);
        }
      }
      int v = m*32 + m32;
      #pragma unroll
      for (int e2 = 0; e2 < 16; ++e2) {
        int o = ROWF(e2);
        oSl[o*400 + v] = z[e2] + boF[o];
      }
    } else if (m < 14) {
      int mt = m - 12;
      f4v z4 = {};
      #pragma unroll
      for (int p = 0; p < 5; ++p) {
        s8v a = ld8(S + HCV + p*1280 + (mt*16 + r)*40 + q*8);
        s8v b = (p == 0) ? xft : ld8(S + fb[p] + VXA(384 + r, q*8));
        z4 = MF16(a, b, z4);
      }
      #pragma unroll
      for (int e = 0; e < 4; ++e) {
        int o = mt*16 + q*4 + e;
        oSl[o*400 + 384 + r] = z4[e] + boF[o];
      }
    }
  }
}

// Plain transpose kernel: gStage[n][l][o][v] -> out[n][o][v][l] (both sides coalesced)
__global__ __launch_bounds__(256) void finT(float* __restrict__ out) {
  int idx = blockIdx.x*256 + threadIdx.x;      // n*12800 + ov
  int n = idx / 12800, ov = idx - n*12800;
  const float* src = gStage + (long)n*153600 + ov;
  float vals[12];
  #pragma unroll
  for (int l = 0; l < 12; ++l) vals[l] = src[(long)l*12800];
  float4* dst = (float4*)(out + (long)idx*12);
  dst[0] = make_float4(vals[0],vals[1],vals[2],vals[3]);
  dst[1] = make_float4(vals[4],vals[5],vals[6],vals[7]);
  dst[2] = make_float4(vals[8],vals[9],vals[10],vals[11]);
}

extern "C" void kernel_launch(void* const* d_in, const int* in_sizes, int n_in,
                              void* d_out, int out_size, void* d_ws, size_t ws_size,
                              hipStream_t stream) {
  (void)in_sizes; (void)n_in; (void)out_size; (void)d_ws; (void)ws_size;
  dymix<<<dim3(384), dim3(TT), 0, stream>>>(
      (const float*)d_in[0],
      (const float*)d_in[1], (const float*)d_in[2],
      (const float*)d_in[3], (const float*)d_in[4],
      (const float*)d_in[5], (const float*)d_in[6],
      (const float*)d_in[7], (const float*)d_in[8]);
  finT<<<dim3(1600), dim3(256), 0, stream>>>((float*)d_out);
}